// Round 12
// baseline (326.892 us; speedup 1.0000x reference)
//
#include <hip/hip_runtime.h>

typedef unsigned short u16;
typedef __attribute__((ext_vector_type(8))) short bf16x8;
typedef __attribute__((ext_vector_type(4))) float f32x4;

// Problem: B=8, S=1024, D=1024, H=16, DK=64.
// d_in = {mask:int32, x:f32, wq:f32, wk:f32, wv:f32, wo:f32}. Output: float32.
// Compute path: f32 -> bf16, MFMA 16x16x32 bf16, fp32 accumulate.
// NOTE (R9): hipLaunchCooperativeKernel silently failed in this harness — do not use.
// Session ledger: R5 32q/wave WIN (498->334). R6 attn XCD-locality WIN (334->329). R7 VALU trim
// net-zero. R8 64q/wave WIN (329->325.4, session best). R9 attn dbuf NEUTRAL-NEG (latency already
// hidden at 8 waves/CU). R11 mask-fold-into-qkv HARMFUL (qkv FETCH 49->66MB: mask stream evicts
// A-panels from per-XCD L2; serial mask tail). R12: exact revert to R8 config.
// Future lever (untried fix): 8-phase 256-tile qkv failed twice with column-major XCD swizzle
// streaming all of A per XCD (FETCH 103MB, HBM-latency loads starved the 2-phase vmcnt lead);
// a chunked per-XCD swizzle would keep A L2-resident — left for a future session.

#if __has_builtin(__builtin_amdgcn_exp2f)
#define EXP2F(x) __builtin_amdgcn_exp2f(x)
#else
#define EXP2F(x) __expf((x) * 0.69314718056f)
#endif

static __device__ __forceinline__ u16 f2bf(float f) {
    union { float f; unsigned u; } v; v.f = f;
    unsigned r = v.u + 0x7fffu + ((v.u >> 16) & 1u);
    return (u16)(r >> 16);
}

static __device__ __forceinline__ f32x4 mfma16(bf16x8 a, bf16x8 b, f32x4 c) {
    return __builtin_amdgcn_mfma_f32_16x16x32_bf16(a, b, c, 0, 0, 0);
}

// async global->LDS, 16 bytes per lane (global_load_lds_dwordx4)
static __device__ __forceinline__ void load_lds16(const u16* g, u16* l) {
    __builtin_amdgcn_global_load_lds((const __attribute__((address_space(1))) unsigned*)(const void*)g,
                                     (__attribute__((address_space(3))) unsigned*)(void*)l, 16, 0, 0);
}

// ---------------- fused prep: cvt_x | cvt_w | pack_mask | zero sums ----------------
// grid 57344: [0,8192) cvt_x, [8192,24576) cvt_w, [24576,57344) pack_mask
__global__ __launch_bounds__(256) void prep_kernel(const float* __restrict__ x,
                                                   const float* __restrict__ wq, const float* __restrict__ wk,
                                                   const float* __restrict__ wv, const float* __restrict__ wo,
                                                   const int* __restrict__ mask,
                                                   u16* __restrict__ xb, u16* __restrict__ wt,
                                                   u16* __restrict__ wot, uint2* __restrict__ mb,
                                                   float* __restrict__ sums) {
    int bid = blockIdx.x;
    if (bid == 0 && threadIdx.x < 16) sums[threadIdx.x] = 0.f;  // zero LN accumulators
    if (bid < 8192) {
        int i = (bid * 256 + threadIdx.x) * 4;  // 8388608 elems
        float4 v = *(const float4*)(x + i);
        ushort4 o;
        o.x = f2bf(v.x); o.y = f2bf(v.y); o.z = f2bf(v.z); o.w = f2bf(v.w);
        *(ushort4*)(xb + i) = o;
    } else if (bid < 24576) {
        int o = (bid - 8192) * 256 + threadIdx.x;  // 4194304 elems
        if (o < 3145728) {
            int z = o >> 20;
            int rem = o & 1048575;
            int n = rem >> 10;
            int d = rem & 1023;
            int h = n >> 6, kk = n & 63;
            const float* w = (z == 0) ? wq : (z == 1) ? wk : wv;
            wt[o] = f2bf(w[h * 65536 + d * 64 + kk]);
        } else {
            int oo = o - 3145728;
            int n = oo >> 10, d = oo & 1023;
            wot[oo] = f2bf(wo[d * 1024 + n]);
        }
    } else {
        long long wi = (long long)(bid - 24576) * 4 + (threadIdx.x >> 6);  // 131072 words
        int lane = threadIdx.x & 63;
        int v = mask[wi * 64 + lane];
        unsigned long long bal = __ballot(v != 0);
        if (lane == 0) {
            uint2 o; o.x = (unsigned)bal; o.y = (unsigned)(bal >> 32);
            mb[wi] = o;
        }
    }
}

// ---------------- fused QKV projection GEMM (m97 structure, round-0 known-good) ----------------
// M=8192, N=3072, K=1024. grid (64, 24), block 256 (4 waves).
// Default x-major dispatch keeps each XCD on a fixed set of 8 m-tiles (64%8==0) -> A L2-resident.
// Q pre-scaled by log2(e)/sqrt(DK) = 0.125*1.4426950 (attn consumes base-2 scores).
__global__ __launch_bounds__(256) void qkv_gemm_kernel(const u16* __restrict__ xb, const u16* __restrict__ wt,
                                                       u16* __restrict__ qb, u16* __restrict__ kb,
                                                       u16* __restrict__ vtb) {
    __shared__ __align__(16) u16 As[128 * 64];
    __shared__ __align__(16) u16 Bs[128 * 64];

    int t = threadIdx.x;
    int lane = t & 63, w = t >> 6;
    int wm = w & 1, wn = w >> 1;
    int l16 = lane & 15, quad = lane >> 4;
    int sw = l16 & 7;

    int m0 = blockIdx.x * 128;
    int n0g = blockIdx.y * 128;

    int srow = t >> 3;
    int skp = ((t & 7) ^ (srow & 7)) * 8;
    const u16* ga0 = xb + (m0 + srow) * 1024 + skp;
    const u16* gb0 = wt + (n0g + srow) * 1024 + skp;

    int arow0 = wm * 64 + l16;
    int brow0 = wn * 64 + l16;

    f32x4 acc[4][4];
#pragma unroll
    for (int i = 0; i < 4; ++i)
#pragma unroll
        for (int j = 0; j < 4; ++j) acc[i][j] = (f32x4){0.f, 0.f, 0.f, 0.f};

    for (int kb0 = 0; kb0 < 1024; kb0 += 64) {
        __syncthreads();
#pragma unroll
        for (int c = 0; c < 4; ++c)
            load_lds16(ga0 + c * 32768 + kb0, &As[c * 2048 + t * 8]);
#pragma unroll
        for (int c = 0; c < 4; ++c)
            load_lds16(gb0 + c * 32768 + kb0, &Bs[c * 2048 + t * 8]);
        __syncthreads();

#pragma unroll
        for (int kh = 0; kh < 2; ++kh) {
            int kidx = ((kh << 2) + quad) ^ sw;
            bf16x8 af[4], bfr[4];
#pragma unroll
            for (int i = 0; i < 4; ++i)
                af[i] = *(const bf16x8*)&As[(arow0 + i * 16) * 64 + kidx * 8];
#pragma unroll
            for (int j = 0; j < 4; ++j)
                bfr[j] = *(const bf16x8*)&Bs[(brow0 + j * 16) * 64 + kidx * 8];
#pragma unroll
            for (int i = 0; i < 4; ++i)
#pragma unroll
                for (int j = 0; j < 4; ++j)
                    acc[i][j] = mfma16(af[i], bfr[j], acc[i][j]);
        }
    }

    int z = blockIdx.y >> 3;
    float qscale = (z == 0) ? 0.18033688f : 1.0f;  // 0.125 * log2(e)
#pragma unroll
    for (int j = 0; j < 4; ++j) {
        int ng = n0g + wn * 64 + j * 16 + l16;
        int nl = ng & 1023;
        int h = nl >> 6, kk = nl & 63;
#pragma unroll
        for (int i = 0; i < 4; ++i) {
#pragma unroll
            for (int r = 0; r < 4; ++r) {
                int m = m0 + wm * 64 + i * 16 + quad * 4 + r;
                int b_ = m >> 10, s = m & 1023;
                u16 val = f2bf(acc[i][j][r] * qscale);
                if (z == 0)      qb[((b_ * 16 + h) * 1024 + s) * 64 + kk] = val;
                else if (z == 1) kb[((b_ * 16 + h) * 1024 + s) * 64 + kk] = val;
                else             vtb[((b_ * 16 + h) * 64 + kk) * 1024 + s] = val;
            }
        }
    }
}

// ---------------- flash attention: LDS-staged K/V + bitmask, 64 queries/wave (R8 proven) -----
// 1D grid 512, block 256 = 4 waves; wave: 64 queries (4 M-fragments), 64-key tiles.
// XCD-locality decode: all 4 q-tile blocks of one (b,h) share id%8 -> same XCD.
// Scores arrive in base-2 domain (log2e folded into Q scale); P = exp2(s).
// exp interleaved per-kt column: score liveness 16 VGPR (vs 64 for full-tile scores).
__global__ __launch_bounds__(256) void attn_kernel(const u16* __restrict__ qb, const u16* __restrict__ kb,
                                                   const u16* __restrict__ vtb, const uint2* __restrict__ mb,
                                                   u16* __restrict__ ctx) {
    __shared__ __align__(16) u16 Ks[64 * 64];
    __shared__ __align__(16) u16 Vs[64 * 64];
    __shared__ __align__(16) u16 P[4][64][72];  // rows padded: 36 dw stride -> <=2-way (free)

    int t = threadIdx.x;
    int w = t >> 6, lane = t & 63;
    int l16 = lane & 15, quad = lane >> 4;

    // id = xcd + 8*j + 32*pp : (b,h) pair p = xcd + 8*pp, q-tile j (256 q each). Bijective over [0,512).
    int id = blockIdx.x;
    int xcd = id & 7;
    int j_ = (id >> 3) & 3;
    int pp = id >> 5;
    int p = xcd + 8 * pp;
    int h = p & 15, b = p >> 4;
    int q0 = j_ * 256 + w * 64;

    const u16* Q = qb + (b * 16 + h) * 65536;
    const u16* K = kb + (b * 16 + h) * 65536;
    const u16* Vt = vtb + (b * 16 + h) * 65536;
    const uint2* MB = mb + (b * 1024 + q0) * 16;

    int srow = t >> 3;
    int skp = ((t & 7) ^ (srow & 7)) * 8;
    const u16* gk0 = K + srow * 64 + skp;          // + (k0+c*32)*64
    const u16* gv0 = Vt + srow * 1024 + skp;       // + c*32*1024 + k0

    // Q fragments: 4 M-fragments x 2 K-halves
    bf16x8 qf[4][2];
#pragma unroll
    for (int mr = 0; mr < 4; ++mr) {
        qf[mr][0] = *(const bf16x8*)(Q + (q0 + mr * 16 + l16) * 64 + quad * 8);
        qf[mr][1] = *(const bf16x8*)(Q + (q0 + mr * 16 + l16) * 64 + 32 + quad * 8);
    }

    f32x4 O[4][4];
#pragma unroll
    for (int mr = 0; mr < 4; ++mr)
#pragma unroll
        for (int j = 0; j < 4; ++j) O[mr][j] = (f32x4){0.f, 0.f, 0.f, 0.f};
    float lsum[4][4];
#pragma unroll
    for (int mr = 0; mr < 4; ++mr)
#pragma unroll
        for (int r = 0; r < 4; ++r) lsum[mr][r] = 0.f;

    int sw = l16 & 7;

    for (int kt0 = 0; kt0 < 16; ++kt0) {
        int k0 = kt0 * 64;

        // hoist mask-word loads: issue before the barriers, consume after staging
        uint2 mw[4][4];
#pragma unroll
        for (int mr = 0; mr < 4; ++mr)
#pragma unroll
            for (int r = 0; r < 4; ++r)
                mw[mr][r] = MB[(mr * 16 + quad * 4 + r) * 16 + kt0];

        __syncthreads();
#pragma unroll
        for (int c = 0; c < 2; ++c) {
            load_lds16(gk0 + (k0 + c * 32) * 64, &Ks[c * 2048 + t * 8]);
            load_lds16(gv0 + c * 32 * 1024 + k0, &Vs[c * 2048 + t * 8]);
        }
        __syncthreads();

        // QK^T + exp/pack, interleaved per kt column (16 keys at a time)
#pragma unroll
        for (int kt = 0; kt < 4; ++kt) {
            int row = kt * 16 + l16;
            bf16x8 klo = *(const bf16x8*)&Ks[row * 64 + ((quad ^ sw) * 8)];
            bf16x8 khi = *(const bf16x8*)&Ks[row * 64 + (((4 + quad) ^ sw) * 8)];
            f32x4 scol[4];
#pragma unroll
            for (int mr = 0; mr < 4; ++mr) {
                f32x4 z = {0.f, 0.f, 0.f, 0.f};
                z = mfma16(qf[mr][0], klo, z);
                z = mfma16(qf[mr][1], khi, z);
                scol[mr] = z;
            }
#pragma unroll
            for (int mr = 0; mr < 4; ++mr)
#pragma unroll
                for (int r = 0; r < 4; ++r) {
                    unsigned wsel = (kt < 2) ? mw[mr][r].x : mw[mr][r].y;
                    unsigned bit = (wsel >> ((kt & 1) * 16 + l16)) & 1u;
                    float e = bit ? EXP2F(scol[mr][r]) : 0.f;
                    lsum[mr][r] += e;
                    P[w][mr * 16 + quad * 4 + r][kt * 16 + l16] = f2bf(e);
                }
        }

        // P: C-layout -> A-layout via same-wave LDS round trip (in-order DS pipe, no barrier)
        bf16x8 pf[4][2];
#pragma unroll
        for (int mr = 0; mr < 4; ++mr) {
            pf[mr][0] = *(const bf16x8*)&P[w][mr * 16 + l16][quad * 8];
            pf[mr][1] = *(const bf16x8*)&P[w][mr * 16 + l16][32 + quad * 8];
        }

        __builtin_amdgcn_s_setprio(1);
#pragma unroll
        for (int j = 0; j < 4; ++j) {
            int row = j * 16 + l16;
            bf16x8 vlo = *(const bf16x8*)&Vs[row * 64 + ((quad ^ sw) * 8)];
            bf16x8 vhi = *(const bf16x8*)&Vs[row * 64 + (((4 + quad) ^ sw) * 8)];
#pragma unroll
            for (int mr = 0; mr < 4; ++mr) {
                O[mr][j] = mfma16(pf[mr][0], vlo, O[mr][j]);
                O[mr][j] = mfma16(pf[mr][1], vhi, O[mr][j]);
            }
        }
        __builtin_amdgcn_s_setprio(0);
    }

#pragma unroll
    for (int mr = 0; mr < 4; ++mr)
#pragma unroll
        for (int r = 0; r < 4; ++r) {
            float s = lsum[mr][r];
            s += __shfl_xor(s, 1);
            s += __shfl_xor(s, 2);
            s += __shfl_xor(s, 4);
            s += __shfl_xor(s, 8);
            lsum[mr][r] = s;
        }

#pragma unroll
    for (int mr = 0; mr < 4; ++mr)
#pragma unroll
        for (int r = 0; r < 4; ++r) {
            int sI = q0 + mr * 16 + quad * 4 + r;
            float inv = __builtin_amdgcn_rcpf(lsum[mr][r]);
            int base = (b * 1024 + sI) * 1024 + h * 64;
#pragma unroll
            for (int j = 0; j < 4; ++j)
                ctx[base + j * 16 + l16] = f2bf(O[mr][j][r] * inv);
        }
}

// ---------------- output projection + residual + fused LN partial sums ----------------
// M=8192, N=1024, K=1024. grid (64, 8), block 256. res = ctx @ wo + x (fp32).
__global__ __launch_bounds__(256) void oproj_gemm_kernel(const u16* __restrict__ ctxb, const u16* __restrict__ wot,
                                                         const float* __restrict__ x, float* __restrict__ res,
                                                         float* __restrict__ sums) {
    __shared__ __align__(16) u16 As[128 * 64];
    __shared__ __align__(16) u16 Bs[128 * 64];

    int t = threadIdx.x;
    int lane = t & 63, w = t >> 6;
    int wm = w & 1, wn = w >> 1;
    int l16 = lane & 15, quad = lane >> 4;
    int sw = l16 & 7;

    int m0 = blockIdx.x * 128;
    int n0 = blockIdx.y * 128;

    int srow = t >> 3;
    int skp = ((t & 7) ^ (srow & 7)) * 8;
    const u16* ga0 = ctxb + (m0 + srow) * 1024 + skp;
    const u16* gb0 = wot + (n0 + srow) * 1024 + skp;

    int arow0 = wm * 64 + l16;
    int brow0 = wn * 64 + l16;

    f32x4 acc[4][4];
#pragma unroll
    for (int i = 0; i < 4; ++i)
#pragma unroll
        for (int j = 0; j < 4; ++j) acc[i][j] = (f32x4){0.f, 0.f, 0.f, 0.f};

    for (int kb0 = 0; kb0 < 1024; kb0 += 64) {
        __syncthreads();
#pragma unroll
        for (int c = 0; c < 4; ++c)
            load_lds16(ga0 + c * 32768 + kb0, &As[c * 2048 + t * 8]);
#pragma unroll
        for (int c = 0; c < 4; ++c)
            load_lds16(gb0 + c * 32768 + kb0, &Bs[c * 2048 + t * 8]);
        __syncthreads();

#pragma unroll
        for (int kh = 0; kh < 2; ++kh) {
            int kidx = ((kh << 2) + quad) ^ sw;
            bf16x8 af[4], bfr[4];
#pragma unroll
            for (int i = 0; i < 4; ++i)
                af[i] = *(const bf16x8*)&As[(arow0 + i * 16) * 64 + kidx * 8];
#pragma unroll
            for (int j = 0; j < 4; ++j)
                bfr[j] = *(const bf16x8*)&Bs[(brow0 + j * 16) * 64 + kidx * 8];
#pragma unroll
            for (int i = 0; i < 4; ++i)
#pragma unroll
                for (int j = 0; j < 4; ++j)
                    acc[i][j] = mfma16(af[i], bfr[j], acc[i][j]);
        }
    }

    float ps = 0.f, ps2 = 0.f;
#pragma unroll
    for (int i = 0; i < 4; ++i) {
#pragma unroll
        for (int r = 0; r < 4; ++r) {
            int m = m0 + wm * 64 + i * 16 + quad * 4 + r;
#pragma unroll
            for (int j = 0; j < 4; ++j) {
                int n = n0 + wn * 64 + j * 16 + l16;
                float v = acc[i][j][r] + x[m * 1024 + n];
                res[m * 1024 + n] = v;
                ps += v; ps2 += v * v;
            }
        }
    }

#pragma unroll
    for (int off = 32; off > 0; off >>= 1) {
        ps += __shfl_xor(ps, off);
        ps2 += __shfl_xor(ps2, off);
    }
    __shared__ float ls[4], ls2[4];
    if (lane == 0) { ls[w] = ps; ls2[w] = ps2; }
    __syncthreads();
    if (t == 0) {
        int b = blockIdx.x >> 3;
        atomicAdd(&sums[b * 2 + 0], ls[0] + ls[1] + ls[2] + ls[3]);
        atomicAdd(&sums[b * 2 + 1], ls2[0] + ls2[1] + ls2[2] + ls2[3]);
    }
}

// ---------------- layernorm normalize (float4-vectorized) ----------------
__global__ __launch_bounds__(256) void norm_kernel(const float* __restrict__ res, const float* __restrict__ sums,
                                                   float* __restrict__ out) {
    int i = (blockIdx.x * 256 + threadIdx.x) * 4;  // grid 8192 -> 8388608
    int b = i >> 20;
    float mean = sums[b * 2 + 0] * (1.0f / 1048576.0f);
    float var = sums[b * 2 + 1] * (1.0f / 1048576.0f) - mean * mean;
    float rs = rsqrtf(var + 1e-5f);
    float4 v = *(const float4*)(res + i);
    float4 o;
    o.x = (v.x - mean) * rs;
    o.y = (v.y - mean) * rs;
    o.z = (v.z - mean) * rs;
    o.w = (v.w - mean) * rs;
    *(float4*)(out + i) = o;
}

// ---------------- launch ----------------

extern "C" void kernel_launch(void* const* d_in, const int* in_sizes, int n_in,
                              void* d_out, int out_size, void* d_ws, size_t ws_size,
                              hipStream_t stream) {
    const int* mask  = (const int*)d_in[0];
    const float* x   = (const float*)d_in[1];
    const float* wq  = (const float*)d_in[2];
    const float* wk  = (const float*)d_in[3];
    const float* wv  = (const float*)d_in[4];
    const float* wo  = (const float*)d_in[5];
    float* out = (float*)d_out;

    char* ws = (char*)d_ws;
    u16* xb    = (u16*)(ws + 0);          // 16,777,216 B
    u16* wt    = (u16*)(ws + 16777216);   //  6,291,456 B
    u16* wot   = (u16*)(ws + 23068672);   //  2,097,152 B
    u16* qb    = (u16*)(ws + 25165824);   // 16,777,216 B
    u16* kb    = (u16*)(ws + 41943040);   // 16,777,216 B
    u16* vtb   = (u16*)(ws + 58720256);   // 16,777,216 B
    float* res = (float*)(ws + 25165824); // 32 MB — aliases qb/kb AFTER attn completes (safe)
    float* sums = (float*)(ws + 75497472);// 64 B
    uint2* mbits = (uint2*)(ws + 76546048); // 1,048,576 B
    u16* ctxb  = (u16*)d_out;             // ctx staged in d_out; overwritten by final norm

    prep_kernel<<<57344, 256, 0, stream>>>(x, wq, wk, wv, wo, mask, xb, wt, wot, mbits, sums);
    qkv_gemm_kernel<<<dim3(64, 24), 256, 0, stream>>>(xb, wt, qb, kb, vtb);
    attn_kernel<<<512, 256, 0, stream>>>(qb, kb, vtb, mbits, ctxb);
    oproj_gemm_kernel<<<dim3(64, 8), 256, 0, stream>>>(ctxb, wot, x, res, sums);
    norm_kernel<<<8192, 256, 0, stream>>>(res, sums, out);
}

// Round 13
// 310.849 us; speedup vs baseline: 1.0516x; 1.0516x over previous
//
#include <hip/hip_runtime.h>

typedef unsigned short u16;
typedef __attribute__((ext_vector_type(8))) short bf16x8;
typedef __attribute__((ext_vector_type(4))) float f32x4;

// Problem: B=8, S=1024, D=1024, H=16, DK=64.
// d_in = {mask:int32, x:f32, wq:f32, wk:f32, wv:f32, wo:f32}. Output: float32.
// Compute path: f32 -> bf16, MFMA 16x16x32 bf16, fp32 accumulate.
// NOTE (R9): hipLaunchCooperativeKernel silently failed in this harness — do not use.
// Session ledger: R5 32q/wave WIN (498->334). R6 attn XCD-locality WIN (334->329). R7 VALU trim
// net-zero. R8 64q/wave WIN (329->325.4, session best). R9 attn dbuf NEUTRAL-NEG. R11 mask-fold
// HARMFUL (evicts A-panels from per-XCD L2). R12 revert = 326.9 (plateau confirmed).
// R13: qkv epilogue vectorization — 64 scalar 2B stores/thread -> z==2: ushort4 direct stores
// (s-contiguous in registers, 64->16); z<2: LDS repack (SM reused post-main-loop, quad-XOR
// swizzle) -> bf16x8 stores (64->8, 128B-contiguous runs per 8 lanes).
// Future lever (untried fix): 8-phase 256-tile qkv failed twice with column-major XCD swizzle
// streaming all of A per XCD; a chunked per-XCD swizzle would keep A L2-resident — future session.

#if __has_builtin(__builtin_amdgcn_exp2f)
#define EXP2F(x) __builtin_amdgcn_exp2f(x)
#else
#define EXP2F(x) __expf((x) * 0.69314718056f)
#endif

static __device__ __forceinline__ u16 f2bf(float f) {
    union { float f; unsigned u; } v; v.f = f;
    unsigned r = v.u + 0x7fffu + ((v.u >> 16) & 1u);
    return (u16)(r >> 16);
}

static __device__ __forceinline__ f32x4 mfma16(bf16x8 a, bf16x8 b, f32x4 c) {
    return __builtin_amdgcn_mfma_f32_16x16x32_bf16(a, b, c, 0, 0, 0);
}

// async global->LDS, 16 bytes per lane (global_load_lds_dwordx4)
static __device__ __forceinline__ void load_lds16(const u16* g, u16* l) {
    __builtin_amdgcn_global_load_lds((const __attribute__((address_space(1))) unsigned*)(const void*)g,
                                     (__attribute__((address_space(3))) unsigned*)(void*)l, 16, 0, 0);
}

// ---------------- fused prep: cvt_x | cvt_w | pack_mask | zero sums ----------------
// grid 57344: [0,8192) cvt_x, [8192,24576) cvt_w, [24576,57344) pack_mask
__global__ __launch_bounds__(256) void prep_kernel(const float* __restrict__ x,
                                                   const float* __restrict__ wq, const float* __restrict__ wk,
                                                   const float* __restrict__ wv, const float* __restrict__ wo,
                                                   const int* __restrict__ mask,
                                                   u16* __restrict__ xb, u16* __restrict__ wt,
                                                   u16* __restrict__ wot, uint2* __restrict__ mb,
                                                   float* __restrict__ sums) {
    int bid = blockIdx.x;
    if (bid == 0 && threadIdx.x < 16) sums[threadIdx.x] = 0.f;  // zero LN accumulators
    if (bid < 8192) {
        int i = (bid * 256 + threadIdx.x) * 4;  // 8388608 elems
        float4 v = *(const float4*)(x + i);
        ushort4 o;
        o.x = f2bf(v.x); o.y = f2bf(v.y); o.z = f2bf(v.z); o.w = f2bf(v.w);
        *(ushort4*)(xb + i) = o;
    } else if (bid < 24576) {
        int o = (bid - 8192) * 256 + threadIdx.x;  // 4194304 elems
        if (o < 3145728) {
            int z = o >> 20;
            int rem = o & 1048575;
            int n = rem >> 10;
            int d = rem & 1023;
            int h = n >> 6, kk = n & 63;
            const float* w = (z == 0) ? wq : (z == 1) ? wk : wv;
            wt[o] = f2bf(w[h * 65536 + d * 64 + kk]);
        } else {
            int oo = o - 3145728;
            int n = oo >> 10, d = oo & 1023;
            wot[oo] = f2bf(wo[d * 1024 + n]);
        }
    } else {
        long long wi = (long long)(bid - 24576) * 4 + (threadIdx.x >> 6);  // 131072 words
        int lane = threadIdx.x & 63;
        int v = mask[wi * 64 + lane];
        unsigned long long bal = __ballot(v != 0);
        if (lane == 0) {
            uint2 o; o.x = (unsigned)bal; o.y = (unsigned)(bal >> 32);
            mb[wi] = o;
        }
    }
}

// ---------------- fused QKV projection GEMM (m97 structure) + vectorized epilogue ------------
// M=8192, N=3072, K=1024. grid (64, 24), block 256 (4 waves).
// Default x-major dispatch keeps each XCD on a fixed set of 8 m-tiles (64%8==0) -> A L2-resident.
// Q pre-scaled by log2(e)/sqrt(DK) = 0.125*1.4426950 (attn consumes base-2 scores).
// Epilogue: z==2 -> ushort4 direct (acc[i][j][0..3] are 4 consecutive s); z<2 -> LDS repack
// (SM reused, phys col = nl ^ (quad<<4) bank swizzle) -> bf16x8 coalesced stores.
__global__ __launch_bounds__(256) void qkv_gemm_kernel(const u16* __restrict__ xb, const u16* __restrict__ wt,
                                                       u16* __restrict__ qb, u16* __restrict__ kb,
                                                       u16* __restrict__ vtb) {
    __shared__ __align__(16) u16 SM[2 * 128 * 64];  // main loop: As|Bs; epilogue: 128x128 repack
    u16* As = SM;
    u16* Bs = SM + 128 * 64;

    int t = threadIdx.x;
    int lane = t & 63, w = t >> 6;
    int wm = w & 1, wn = w >> 1;
    int l16 = lane & 15, quad = lane >> 4;
    int sw = l16 & 7;

    int m0 = blockIdx.x * 128;
    int n0g = blockIdx.y * 128;

    int srow = t >> 3;
    int skp = ((t & 7) ^ (srow & 7)) * 8;
    const u16* ga0 = xb + (m0 + srow) * 1024 + skp;
    const u16* gb0 = wt + (n0g + srow) * 1024 + skp;

    int arow0 = wm * 64 + l16;
    int brow0 = wn * 64 + l16;

    f32x4 acc[4][4];
#pragma unroll
    for (int i = 0; i < 4; ++i)
#pragma unroll
        for (int j = 0; j < 4; ++j) acc[i][j] = (f32x4){0.f, 0.f, 0.f, 0.f};

    for (int kb0 = 0; kb0 < 1024; kb0 += 64) {
        __syncthreads();
#pragma unroll
        for (int c = 0; c < 4; ++c)
            load_lds16(ga0 + c * 32768 + kb0, &As[c * 2048 + t * 8]);
#pragma unroll
        for (int c = 0; c < 4; ++c)
            load_lds16(gb0 + c * 32768 + kb0, &Bs[c * 2048 + t * 8]);
        __syncthreads();

#pragma unroll
        for (int kh = 0; kh < 2; ++kh) {
            int kidx = ((kh << 2) + quad) ^ sw;
            bf16x8 af[4], bfr[4];
#pragma unroll
            for (int i = 0; i < 4; ++i)
                af[i] = *(const bf16x8*)&As[(arow0 + i * 16) * 64 + kidx * 8];
#pragma unroll
            for (int j = 0; j < 4; ++j)
                bfr[j] = *(const bf16x8*)&Bs[(brow0 + j * 16) * 64 + kidx * 8];
#pragma unroll
            for (int i = 0; i < 4; ++i)
#pragma unroll
                for (int j = 0; j < 4; ++j)
                    acc[i][j] = mfma16(af[i], bfr[j], acc[i][j]);
        }
    }

    int z = blockIdx.y >> 3;
    if (z == 2) {
        // vtb[((b*16+h)*64+kk)*1024 + s]: acc[i][j][0..3] are s, s+1, s+2, s+3 -> ushort4
#pragma unroll
        for (int j = 0; j < 4; ++j) {
            int ng = (n0g + wn * 64 + j * 16 + l16) & 1023;
            int h = ng >> 6, kk = ng & 63;
#pragma unroll
            for (int i = 0; i < 4; ++i) {
                int m = m0 + wm * 64 + i * 16 + quad * 4;
                int b_ = m >> 10, s = m & 1023;
                ushort4 o4;
                o4.x = f2bf(acc[i][j][0]);
                o4.y = f2bf(acc[i][j][1]);
                o4.z = f2bf(acc[i][j][2]);
                o4.w = f2bf(acc[i][j][3]);
                *(ushort4*)&vtb[((b_ * 16 + h) * 64 + kk) * 1024 + s] = o4;
            }
        }
    } else {
        float qscale = (z == 0) ? 0.18033688f : 1.0f;  // 0.125 * log2(e)
        u16* dst = (z == 0) ? qb : kb;
        __syncthreads();  // all waves done reading As/Bs before repack overwrite
#pragma unroll
        for (int j = 0; j < 4; ++j) {
            int nl_ = wn * 64 + j * 16 + l16;
#pragma unroll
            for (int i = 0; i < 4; ++i)
#pragma unroll
                for (int r = 0; r < 4; ++r) {
                    int ml_ = wm * 64 + i * 16 + quad * 4 + r;
                    // phys col = nl ^ (quad(ml)<<4): quads land 8 banks apart -> conflict-free
                    SM[ml_ * 128 + (nl_ ^ (((ml_ >> 2) & 3) << 4))] = f2bf(acc[i][j][r] * qscale);
                }
        }
        __syncthreads();
        // readout: thread -> (row = t>>4 + e*16, chunk = t&15); 8 lanes = 128B contiguous run
        int cc = t & 15;
        int r0 = t >> 4;
#pragma unroll
        for (int e = 0; e < 8; ++e) {
            int row = r0 + e * 16;
            int m = m0 + row;
            int b_ = m >> 10, s = m & 1023;
            int nloc = cc * 8;
            int ng = (n0g + nloc) & 1023;
            int h = ng >> 6, kk = ng & 63;
            bf16x8 v = *(const bf16x8*)&SM[row * 128 + (nloc ^ (((row >> 2) & 3) << 4))];
            *(bf16x8*)&dst[((b_ * 16 + h) * 1024 + s) * 64 + kk] = v;
        }
    }
}

// ---------------- flash attention: LDS-staged K/V + bitmask, 64 queries/wave (R8 proven) -----
// 1D grid 512, block 256 = 4 waves; wave: 64 queries (4 M-fragments), 64-key tiles.
// XCD-locality decode: all 4 q-tile blocks of one (b,h) share id%8 -> same XCD.
// Scores arrive in base-2 domain (log2e folded into Q scale); P = exp2(s).
// exp interleaved per-kt column: score liveness 16 VGPR (vs 64 for full-tile scores).
__global__ __launch_bounds__(256) void attn_kernel(const u16* __restrict__ qb, const u16* __restrict__ kb,
                                                   const u16* __restrict__ vtb, const uint2* __restrict__ mb,
                                                   u16* __restrict__ ctx) {
    __shared__ __align__(16) u16 Ks[64 * 64];
    __shared__ __align__(16) u16 Vs[64 * 64];
    __shared__ __align__(16) u16 P[4][64][72];  // rows padded: 36 dw stride -> <=2-way (free)

    int t = threadIdx.x;
    int w = t >> 6, lane = t & 63;
    int l16 = lane & 15, quad = lane >> 4;

    // id = xcd + 8*j + 32*pp : (b,h) pair p = xcd + 8*pp, q-tile j (256 q each). Bijective over [0,512).
    int id = blockIdx.x;
    int xcd = id & 7;
    int j_ = (id >> 3) & 3;
    int pp = id >> 5;
    int p = xcd + 8 * pp;
    int h = p & 15, b = p >> 4;
    int q0 = j_ * 256 + w * 64;

    const u16* Q = qb + (b * 16 + h) * 65536;
    const u16* K = kb + (b * 16 + h) * 65536;
    const u16* Vt = vtb + (b * 16 + h) * 65536;
    const uint2* MB = mb + (b * 1024 + q0) * 16;

    int srow = t >> 3;
    int skp = ((t & 7) ^ (srow & 7)) * 8;
    const u16* gk0 = K + srow * 64 + skp;          // + (k0+c*32)*64
    const u16* gv0 = Vt + srow * 1024 + skp;       // + c*32*1024 + k0

    // Q fragments: 4 M-fragments x 2 K-halves
    bf16x8 qf[4][2];
#pragma unroll
    for (int mr = 0; mr < 4; ++mr) {
        qf[mr][0] = *(const bf16x8*)(Q + (q0 + mr * 16 + l16) * 64 + quad * 8);
        qf[mr][1] = *(const bf16x8*)(Q + (q0 + mr * 16 + l16) * 64 + 32 + quad * 8);
    }

    f32x4 O[4][4];
#pragma unroll
    for (int mr = 0; mr < 4; ++mr)
#pragma unroll
        for (int j = 0; j < 4; ++j) O[mr][j] = (f32x4){0.f, 0.f, 0.f, 0.f};
    float lsum[4][4];
#pragma unroll
    for (int mr = 0; mr < 4; ++mr)
#pragma unroll
        for (int r = 0; r < 4; ++r) lsum[mr][r] = 0.f;

    int sw = l16 & 7;

    for (int kt0 = 0; kt0 < 16; ++kt0) {
        int k0 = kt0 * 64;

        // hoist mask-word loads: issue before the barriers, consume after staging
        uint2 mw[4][4];
#pragma unroll
        for (int mr = 0; mr < 4; ++mr)
#pragma unroll
            for (int r = 0; r < 4; ++r)
                mw[mr][r] = MB[(mr * 16 + quad * 4 + r) * 16 + kt0];

        __syncthreads();
#pragma unroll
        for (int c = 0; c < 2; ++c) {
            load_lds16(gk0 + (k0 + c * 32) * 64, &Ks[c * 2048 + t * 8]);
            load_lds16(gv0 + c * 32 * 1024 + k0, &Vs[c * 2048 + t * 8]);
        }
        __syncthreads();

        // QK^T + exp/pack, interleaved per kt column (16 keys at a time)
#pragma unroll
        for (int kt = 0; kt < 4; ++kt) {
            int row = kt * 16 + l16;
            bf16x8 klo = *(const bf16x8*)&Ks[row * 64 + ((quad ^ sw) * 8)];
            bf16x8 khi = *(const bf16x8*)&Ks[row * 64 + (((4 + quad) ^ sw) * 8)];
            f32x4 scol[4];
#pragma unroll
            for (int mr = 0; mr < 4; ++mr) {
                f32x4 z = {0.f, 0.f, 0.f, 0.f};
                z = mfma16(qf[mr][0], klo, z);
                z = mfma16(qf[mr][1], khi, z);
                scol[mr] = z;
            }
#pragma unroll
            for (int mr = 0; mr < 4; ++mr)
#pragma unroll
                for (int r = 0; r < 4; ++r) {
                    unsigned wsel = (kt < 2) ? mw[mr][r].x : mw[mr][r].y;
                    unsigned bit = (wsel >> ((kt & 1) * 16 + l16)) & 1u;
                    float e = bit ? EXP2F(scol[mr][r]) : 0.f;
                    lsum[mr][r] += e;
                    P[w][mr * 16 + quad * 4 + r][kt * 16 + l16] = f2bf(e);
                }
        }

        // P: C-layout -> A-layout via same-wave LDS round trip (in-order DS pipe, no barrier)
        bf16x8 pf[4][2];
#pragma unroll
        for (int mr = 0; mr < 4; ++mr) {
            pf[mr][0] = *(const bf16x8*)&P[w][mr * 16 + l16][quad * 8];
            pf[mr][1] = *(const bf16x8*)&P[w][mr * 16 + l16][32 + quad * 8];
        }

        __builtin_amdgcn_s_setprio(1);
#pragma unroll
        for (int j = 0; j < 4; ++j) {
            int row = j * 16 + l16;
            bf16x8 vlo = *(const bf16x8*)&Vs[row * 64 + ((quad ^ sw) * 8)];
            bf16x8 vhi = *(const bf16x8*)&Vs[row * 64 + (((4 + quad) ^ sw) * 8)];
#pragma unroll
            for (int mr = 0; mr < 4; ++mr) {
                O[mr][j] = mfma16(pf[mr][0], vlo, O[mr][j]);
                O[mr][j] = mfma16(pf[mr][1], vhi, O[mr][j]);
            }
        }
        __builtin_amdgcn_s_setprio(0);
    }

#pragma unroll
    for (int mr = 0; mr < 4; ++mr)
#pragma unroll
        for (int r = 0; r < 4; ++r) {
            float s = lsum[mr][r];
            s += __shfl_xor(s, 1);
            s += __shfl_xor(s, 2);
            s += __shfl_xor(s, 4);
            s += __shfl_xor(s, 8);
            lsum[mr][r] = s;
        }

#pragma unroll
    for (int mr = 0; mr < 4; ++mr)
#pragma unroll
        for (int r = 0; r < 4; ++r) {
            int sI = q0 + mr * 16 + quad * 4 + r;
            float inv = __builtin_amdgcn_rcpf(lsum[mr][r]);
            int base = (b * 1024 + sI) * 1024 + h * 64;
#pragma unroll
            for (int j = 0; j < 4; ++j)
                ctx[base + j * 16 + l16] = f2bf(O[mr][j][r] * inv);
        }
}

// ---------------- output projection + residual + fused LN partial sums ----------------
// M=8192, N=1024, K=1024. grid (64, 8), block 256. res = ctx @ wo + x (fp32).
__global__ __launch_bounds__(256) void oproj_gemm_kernel(const u16* __restrict__ ctxb, const u16* __restrict__ wot,
                                                         const float* __restrict__ x, float* __restrict__ res,
                                                         float* __restrict__ sums) {
    __shared__ __align__(16) u16 As[128 * 64];
    __shared__ __align__(16) u16 Bs[128 * 64];

    int t = threadIdx.x;
    int lane = t & 63, w = t >> 6;
    int wm = w & 1, wn = w >> 1;
    int l16 = lane & 15, quad = lane >> 4;
    int sw = l16 & 7;

    int m0 = blockIdx.x * 128;
    int n0 = blockIdx.y * 128;

    int srow = t >> 3;
    int skp = ((t & 7) ^ (srow & 7)) * 8;
    const u16* ga0 = ctxb + (m0 + srow) * 1024 + skp;
    const u16* gb0 = wot + (n0 + srow) * 1024 + skp;

    int arow0 = wm * 64 + l16;
    int brow0 = wn * 64 + l16;

    f32x4 acc[4][4];
#pragma unroll
    for (int i = 0; i < 4; ++i)
#pragma unroll
        for (int j = 0; j < 4; ++j) acc[i][j] = (f32x4){0.f, 0.f, 0.f, 0.f};

    for (int kb0 = 0; kb0 < 1024; kb0 += 64) {
        __syncthreads();
#pragma unroll
        for (int c = 0; c < 4; ++c)
            load_lds16(ga0 + c * 32768 + kb0, &As[c * 2048 + t * 8]);
#pragma unroll
        for (int c = 0; c < 4; ++c)
            load_lds16(gb0 + c * 32768 + kb0, &Bs[c * 2048 + t * 8]);
        __syncthreads();

#pragma unroll
        for (int kh = 0; kh < 2; ++kh) {
            int kidx = ((kh << 2) + quad) ^ sw;
            bf16x8 af[4], bfr[4];
#pragma unroll
            for (int i = 0; i < 4; ++i)
                af[i] = *(const bf16x8*)&As[(arow0 + i * 16) * 64 + kidx * 8];
#pragma unroll
            for (int j = 0; j < 4; ++j)
                bfr[j] = *(const bf16x8*)&Bs[(brow0 + j * 16) * 64 + kidx * 8];
#pragma unroll
            for (int i = 0; i < 4; ++i)
#pragma unroll
                for (int j = 0; j < 4; ++j)
                    acc[i][j] = mfma16(af[i], bfr[j], acc[i][j]);
        }
    }

    float ps = 0.f, ps2 = 0.f;
#pragma unroll
    for (int i = 0; i < 4; ++i) {
#pragma unroll
        for (int r = 0; r < 4; ++r) {
            int m = m0 + wm * 64 + i * 16 + quad * 4 + r;
#pragma unroll
            for (int j = 0; j < 4; ++j) {
                int n = n0 + wn * 64 + j * 16 + l16;
                float v = acc[i][j][r] + x[m * 1024 + n];
                res[m * 1024 + n] = v;
                ps += v; ps2 += v * v;
            }
        }
    }

#pragma unroll
    for (int off = 32; off > 0; off >>= 1) {
        ps += __shfl_xor(ps, off);
        ps2 += __shfl_xor(ps2, off);
    }
    __shared__ float ls[4], ls2[4];
    if (lane == 0) { ls[w] = ps; ls2[w] = ps2; }
    __syncthreads();
    if (t == 0) {
        int b = blockIdx.x >> 3;
        atomicAdd(&sums[b * 2 + 0], ls[0] + ls[1] + ls[2] + ls[3]);
        atomicAdd(&sums[b * 2 + 1], ls2[0] + ls2[1] + ls2[2] + ls2[3]);
    }
}

// ---------------- layernorm normalize (float4-vectorized) ----------------
__global__ __launch_bounds__(256) void norm_kernel(const float* __restrict__ res, const float* __restrict__ sums,
                                                   float* __restrict__ out) {
    int i = (blockIdx.x * 256 + threadIdx.x) * 4;  // grid 8192 -> 8388608
    int b = i >> 20;
    float mean = sums[b * 2 + 0] * (1.0f / 1048576.0f);
    float var = sums[b * 2 + 1] * (1.0f / 1048576.0f) - mean * mean;
    float rs = rsqrtf(var + 1e-5f);
    float4 v = *(const float4*)(res + i);
    float4 o;
    o.x = (v.x - mean) * rs;
    o.y = (v.y - mean) * rs;
    o.z = (v.z - mean) * rs;
    o.w = (v.w - mean) * rs;
    *(float4*)(out + i) = o;
}

// ---------------- launch ----------------

extern "C" void kernel_launch(void* const* d_in, const int* in_sizes, int n_in,
                              void* d_out, int out_size, void* d_ws, size_t ws_size,
                              hipStream_t stream) {
    const int* mask  = (const int*)d_in[0];
    const float* x   = (const float*)d_in[1];
    const float* wq  = (const float*)d_in[2];
    const float* wk  = (const float*)d_in[3];
    const float* wv  = (const float*)d_in[4];
    const float* wo  = (const float*)d_in[5];
    float* out = (float*)d_out;

    char* ws = (char*)d_ws;
    u16* xb    = (u16*)(ws + 0);          // 16,777,216 B
    u16* wt    = (u16*)(ws + 16777216);   //  6,291,456 B
    u16* wot   = (u16*)(ws + 23068672);   //  2,097,152 B
    u16* qb    = (u16*)(ws + 25165824);   // 16,777,216 B
    u16* kb    = (u16*)(ws + 41943040);   // 16,777,216 B
    u16* vtb   = (u16*)(ws + 58720256);   // 16,777,216 B
    float* res = (float*)(ws + 25165824); // 32 MB — aliases qb/kb AFTER attn completes (safe)
    float* sums = (float*)(ws + 75497472);// 64 B
    uint2* mbits = (uint2*)(ws + 76546048); // 1,048,576 B
    u16* ctxb  = (u16*)d_out;             // ctx staged in d_out; overwritten by final norm

    prep_kernel<<<57344, 256, 0, stream>>>(x, wq, wk, wv, wo, mask, xb, wt, wot, mbits, sums);
    qkv_gemm_kernel<<<dim3(64, 24), 256, 0, stream>>>(xb, wt, qb, kb, vtb);
    attn_kernel<<<512, 256, 0, stream>>>(qb, kb, vtb, mbits, ctxb);
    oproj_gemm_kernel<<<dim3(64, 8), 256, 0, stream>>>(ctxb, wot, x, res, sums);
    norm_kernel<<<8192, 256, 0, stream>>>(res, sums, out);
}